// Round 6
// baseline (146.603 us; speedup 1.0000x reference)
//
#include <hip/hip_runtime.h>
#include <hip/hip_bf16.h>
#include <math.h>

#define TT    1024   // B*S tokens
#define DD    768    // hidden dim
#define NHEAD 12
#define HDIM  64
#define NBLK  16
#define NMID  14
#define NCOUT 16

typedef __attribute__((ext_vector_type(4))) float f32x4;
typedef __attribute__((ext_vector_type(8))) short bfrag;   // 8 bf16 = 4 VGPRs

#define MFMA(a, b, c) __builtin_amdgcn_mfma_f32_16x16x32_bf16(a, b, c, 0, 0, 0)

__device__ __forceinline__ bfrag ldg8(const ushort* p) { return *(const bfrag*)p; }
__device__ __forceinline__ ushort f2bf(float f) {
    __hip_bfloat16 h = __float2bfloat16(f);
    return *(ushort*)&h;
}

// ---------------------------------------------------------------------------
// Fused prep: blocks [0,768) convert X fp32->bf16; [768,3648) transpose the
// 5 big weight matrices W[k][n] -> WT[n][k] bf16; [3648,3660) build WcT.
// ---------------------------------------------------------------------------
__global__ __launch_bounds__(256) void prep_k(
    const float* __restrict__ X,
    const float* __restrict__ Wq, const float* __restrict__ Wk,
    const float* __restrict__ Wv, const float* __restrict__ Wo,
    const float* __restrict__ Wd, const float* __restrict__ Wc,
    ushort* __restrict__ xb,
    ushort* __restrict__ qT, ushort* __restrict__ kT, ushort* __restrict__ vT,
    ushort* __restrict__ oT, ushort* __restrict__ dT, ushort* __restrict__ cT)
{
    __shared__ float t[32][33];
    int bx = blockIdx.x;
    if (bx < 768) {                                  // X conversion
        int i = bx * 256 + threadIdx.x;              // float4 index
        float4 f = ((const float4*)X)[i];
        ushort4 u;
        u.x = f2bf(f.x); u.y = f2bf(f.y); u.z = f2bf(f.z); u.w = f2bf(f.w);
        ((ushort4*)xb)[i] = u;
        return;
    }
    if (bx >= 3648) {                                // WcT: 16x768 from 768x16
        int i = bx - 3648;                           // 0..11, 64 k-rows each
        #pragma unroll
        for (int m = 0; m < 4; m++) {
            int idx = threadIdx.x + m * 256;         // 0..1023
            int k = i * 64 + (idx >> 4), c = idx & 15;
            cT[c * DD + k] = f2bf(Wc[k * NCOUT + c]);
        }
        return;
    }
    int bz = bx - 768;                               // 0..2879
    int z = bz / 576;
    int rem = bz % 576;
    int k0 = (rem / 24) * 32, n0 = (rem % 24) * 32;
    const float* W; ushort* O;
    if (z == 0)      { W = Wq; O = qT; }
    else if (z == 1) { W = Wk; O = kT; }
    else if (z == 2) { W = Wv; O = vT; }
    else if (z == 3) { W = Wo; O = oT; }
    else             { W = Wd; O = dT; }
    int tx = threadIdx.x & 31, ty = threadIdx.x >> 5;   // ty 0..7
    #pragma unroll
    for (int i = 0; i < 4; i++)
        t[ty + i * 8][tx] = W[(k0 + ty + i * 8) * DD + n0 + tx];
    __syncthreads();
    #pragma unroll
    for (int i = 0; i < 4; i++)
        O[(n0 + ty + i * 8) * DD + k0 + tx] = f2bf(t[tx][ty + i * 8]);
}

// ---------------------------------------------------------------------------
// QKV MFMA GEMM: xb[1024][768] @ W^T -> q,k [H][T][64], v as vT [H][64][T].
// Grid (16, 12, 3); 4 waves, each 32x32 of a 64x64 tile. No LDS.
// ---------------------------------------------------------------------------
__global__ __launch_bounds__(256) void qkv_mfma_k(
    const ushort* __restrict__ xb,
    const ushort* __restrict__ wqT, const ushort* __restrict__ wkT,
    const ushort* __restrict__ wvT,
    const float* __restrict__ bq, const float* __restrict__ bk,
    const float* __restrict__ bv,
    ushort* __restrict__ qo, ushort* __restrict__ ko, ushort* __restrict__ vTo)
{
    int z = blockIdx.z;
    const ushort* BT = (z == 0) ? wqT : (z == 1) ? wkT : wvT;
    const float* bias = (z == 0) ? bq : (z == 1) ? bk : bv;

    int lane = threadIdx.x & 63, w = threadIdx.x >> 6;
    int lr = lane & 15, lg = lane >> 4;
    int row0 = blockIdx.x * 64 + (w >> 1) * 32;
    int h = blockIdx.y;
    int col0 = h * 64 + (w & 1) * 32;

    f32x4 acc00 = {0,0,0,0}, acc01 = {0,0,0,0}, acc10 = {0,0,0,0}, acc11 = {0,0,0,0};
    const ushort* a0p = xb + (size_t)(row0 + lr) * DD + lg * 8;
    const ushort* a1p = a0p + 16 * DD;
    const ushort* b0p = BT + (size_t)(col0 + lr) * DD + lg * 8;
    const ushort* b1p = b0p + 16 * DD;
    #pragma unroll 4
    for (int k0 = 0; k0 < DD; k0 += 32) {
        bfrag a0 = ldg8(a0p + k0), a1 = ldg8(a1p + k0);
        bfrag b0 = ldg8(b0p + k0), b1 = ldg8(b1p + k0);
        acc00 = MFMA(a0, b0, acc00); acc01 = MFMA(a0, b1, acc01);
        acc10 = MFMA(a1, b0, acc10); acc11 = MFMA(a1, b1, acc11);
    }
    #pragma unroll
    for (int mt = 0; mt < 2; mt++) {
        #pragma unroll
        for (int nt = 0; nt < 2; nt++) {
            f32x4 acc = (mt == 0) ? (nt == 0 ? acc00 : acc01)
                                  : (nt == 0 ? acc10 : acc11);
            #pragma unroll
            for (int j = 0; j < 4; j++) {
                int r = row0 + mt * 16 + lg * 4 + j;
                int c = col0 + nt * 16 + lr;            // global col
                ushort u = f2bf(acc[j] + bias[c]);
                int cc = c - h * 64;                    // col within head
                if (z == 2)      vTo[(size_t)(h * 64 + cc) * TT + r] = u;
                else if (z == 0) qo[(size_t)(h * TT + r) * 64 + cc] = u;
                else             ko[(size_t)(h * TT + r) * 64 + cc] = u;
            }
        }
    }
}

// ---------------------------------------------------------------------------
// Attention wave core (k-split): 16 q-rows vs NKB key blocks.
// S = Q K^T via MFMA -> scale/mask/exp -> P (bf16, swizzled per-wave LDS)
// -> O += P V via MFMA. Partial o/lsum merge by plain add (no-max softmax).
// ---------------------------------------------------------------------------
template <int NKB>
__device__ __forceinline__ void attn_core(
    const ushort* __restrict__ kbf, const ushort* __restrict__ vT,
    const int* __restrict__ mask, const int kblk[NKB], int h,
    bfrag aq0, bfrag aq1, ushort* __restrict__ Pw,
    f32x4 (&o)[4], float (&lsum)[4])
{
    int lane = threadIdx.x & 63, lr = lane & 15, lg = lane >> 4;
    #pragma unroll
    for (int kb = 0; kb < NKB; kb++) {
        int bi = kblk[kb];
        #pragma unroll
        for (int kt = 0; kt < 4; kt++) {
            int key = bi * 64 + kt * 16 + lr;
            const ushort* krow = kbf + (size_t)(h * TT + key) * 64 + lg * 8;
            bfrag b0 = ldg8(krow);
            bfrag b1 = ldg8(krow + 32);
            f32x4 s = {0, 0, 0, 0};
            s = MFMA(aq0, b0, s);
            s = MFMA(aq1, b1, s);
            int mk = mask[key];
            #pragma unroll
            for (int j = 0; j < 4; j++) {
                float pv = (mk > 0) ? __expf(s[j] * 0.125f) : 0.0f;
                lsum[j] += pv;
                int row = lg * 4 + j;
                int idx = (row * (NKB * 64) + (kb * 4 + kt) * 16 + lr)
                          ^ ((row & 7) << 3);
                Pw[idx] = f2bf(pv);
            }
        }
    }
    #pragma unroll
    for (int ks = 0; ks < NKB * 2; ks++) {     // 32-key chunks
        int bi = kblk[ks >> 1];
        int pidx = (lr * (NKB * 64) + ks * 32 + lg * 8) ^ ((lr & 7) << 3);
        bfrag pa = *(const bfrag*)(Pw + pidx);
        #pragma unroll
        for (int dt = 0; dt < 4; dt++) {
            const ushort* vrow = vT + (size_t)(h * 64 + dt * 16 + lr) * TT
                               + bi * 64 + (ks & 1) * 32 + lg * 8;
            o[dt] = MFMA(pa, ldg8(vrow), o[dt]);
        }
    }
}

// ---------------------------------------------------------------------------
// Attention, k-split across waves. Grid (64, 12): x = 16-row q-tile, y = head.
// qb = x>>2. Mid (qb 1..14): wave w covers 2 of the 8 gathered key blocks.
// Glob (qb 0,15): wave w covers key blocks 4w..4w+3. The merge buffers alias
// the (then-dead) P buffer: LDS = 32 KB; __launch_bounds__(256,4) caps VGPR
// at 128 -> 4 blocks/CU, 16 waves/CU.
// ---------------------------------------------------------------------------
__global__ __launch_bounds__(256, 4) void attn_k(
    const ushort* __restrict__ qbf, const ushort* __restrict__ kbf,
    const ushort* __restrict__ vT, const int* __restrict__ mask,
    const int* __restrict__ rnd, ushort* __restrict__ ctx)
{
    __shared__ __align__(16) ushort P[4][4096];   // 32KB; aliased for merge
    float* mo = (float*)&P[0][0];                 // [w][dt][j][lane] 16KB
    float* ml = mo + 4096;                        // [w][16]
    int x = blockIdx.x, h = blockIdx.y;
    int w = threadIdx.x >> 6, lane = threadIdx.x & 63;
    int lr = lane & 15, lg = lane >> 4;

    int qtok0 = x * 16;
    int qb = x >> 2;
    const ushort* qrow = qbf + (size_t)(h * TT + qtok0 + lr) * 64 + lg * 8;
    bfrag aq0 = ldg8(qrow);
    bfrag aq1 = ldg8(qrow + 32);

    f32x4 zero = {0, 0, 0, 0};
    f32x4 o[4] = {zero, zero, zero, zero};
    float l[4] = {0.f, 0.f, 0.f, 0.f};

    if (qb >= 1 && qb <= NMID) {
        int n = qb - 1;
        int b0, b1;
        if (w == 0)      { b0 = 0;              b1 = NBLK - 1;       }
        else if (w == 1) { b0 = n;              b1 = n + 1;          }
        else if (w == 2) { b0 = n + 2;          b1 = rnd[n * 3 + 0]; }
        else             { b0 = rnd[n * 3 + 1]; b1 = rnd[n * 3 + 2]; }
        int kblk[2] = { b0, b1 };
        attn_core<2>(kbf, vT, mask, kblk, h, aq0, aq1, &P[w][0], o, l);
    } else {
        int kblk[4] = { w * 4, w * 4 + 1, w * 4 + 2, w * 4 + 3 };
        attn_core<4>(kbf, vT, mask, kblk, h, aq0, aq1, &P[w][0], o, l);
    }

    // wave-local row-sum reduce (over lr bits)
    #pragma unroll
    for (int j = 0; j < 4; j++) {
        float s = l[j];
        s += __shfl_xor(s, 1); s += __shfl_xor(s, 2);
        s += __shfl_xor(s, 4); s += __shfl_xor(s, 8);
        l[j] = s;
    }
    __syncthreads();          // every wave done reading its P before aliasing
    #pragma unroll
    for (int dt = 0; dt < 4; dt++)
        #pragma unroll
        for (int j = 0; j < 4; j++)
            mo[(((w * 4 + dt) * 4 + j) << 6) + lane] = o[dt][j];
    if (lr == 0) {
        #pragma unroll
        for (int j = 0; j < 4; j++) ml[w * 16 + lg * 4 + j] = l[j];
    }
    __syncthreads();

    // wave w merges + writes output columns w*16 .. w*16+15
    #pragma unroll
    for (int j = 0; j < 4; j++) {
        int row = lg * 4 + j;
        float lt = 1.0f / (ml[row] + ml[16 + row] + ml[32 + row] + ml[48 + row]);
        float of = mo[(((0 * 4 + w) * 4 + j) << 6) + lane]
                 + mo[(((1 * 4 + w) * 4 + j) << 6) + lane]
                 + mo[(((2 * 4 + w) * 4 + j) << 6) + lane]
                 + mo[(((3 * 4 + w) * 4 + j) << 6) + lane];
        ctx[(size_t)(qtok0 + row) * DD + h * 64 + w * 16 + lr] = f2bf(of * lt);
    }
}

// ---------------------------------------------------------------------------
// Fused tail: per 16-row block (grid 64):
//   attnout = ctx @ Wo + bo  -> swizzled LDS (bf16)
//   hs      = attnout @ Wd + bd  (registers, fp32)
//   LN (stats fp32 from registers) -> hsn bf16 -> LDS
//   out     = hsn @ WcT + bc  (wave 0 MFMA, fp32 out)
// ---------------------------------------------------------------------------
#define SWZ(row, col) ((((row) * DD) + (col)) ^ (((row) & 7) << 3))

__global__ __launch_bounds__(256) void tail_k(
    const ushort* __restrict__ ctxb, const ushort* __restrict__ woT,
    const float* __restrict__ bo, const ushort* __restrict__ wdT,
    const float* __restrict__ bd, const float* __restrict__ lng,
    const float* __restrict__ lnb, const ushort* __restrict__ wcT,
    const float* __restrict__ bc, float* __restrict__ out)
{
    __shared__ __align__(16) ushort buf[16 * DD];   // 24KB
    __shared__ float part[2][4][16];
    int w = threadIdx.x >> 6, lane = threadIdx.x & 63;
    int lr = lane & 15, lg = lane >> 4;
    int row0 = blockIdx.x * 16;

    // ---- pass 1: attnout = ctx @ Wo + bo -> buf
    f32x4 acc[12];
    #pragma unroll
    for (int cf = 0; cf < 12; cf++) acc[cf] = (f32x4){0, 0, 0, 0};
    const ushort* ap = ctxb + (size_t)(row0 + lr) * DD + lg * 8;
    #pragma unroll 2
    for (int k0 = 0; k0 < DD; k0 += 32) {
        bfrag a = ldg8(ap + k0);
        #pragma unroll
        for (int cf = 0; cf < 12; cf++) {
            int col = w * 192 + cf * 16 + lr;
            bfrag b = ldg8(woT + (size_t)col * DD + lg * 8 + k0);
            acc[cf] = MFMA(a, b, acc[cf]);
        }
    }
    #pragma unroll
    for (int cf = 0; cf < 12; cf++) {
        int col = w * 192 + cf * 16 + lr;
        float bias = bo[col];
        #pragma unroll
        for (int j = 0; j < 4; j++) {
            int row = lg * 4 + j;
            buf[SWZ(row, col)] = f2bf(acc[cf][j] + bias);
        }
    }
    __syncthreads();

    // ---- pass 2: hs = attnout @ Wd + bd (registers)
    #pragma unroll
    for (int cf = 0; cf < 12; cf++) acc[cf] = (f32x4){0, 0, 0, 0};
    #pragma unroll 2
    for (int k0 = 0; k0 < DD; k0 += 32) {
        bfrag a = *(const bfrag*)&buf[SWZ(lr, k0 + lg * 8)];
        #pragma unroll
        for (int cf = 0; cf < 12; cf++) {
            int col = w * 192 + cf * 16 + lr;
            bfrag b = ldg8(wdT + (size_t)col * DD + lg * 8 + k0);
            acc[cf] = MFMA(a, b, acc[cf]);
        }
    }
    // bias + LN stats from registers (fp32)
    float sum[4] = {0, 0, 0, 0}, sq[4] = {0, 0, 0, 0};
    #pragma unroll
    for (int cf = 0; cf < 12; cf++) {
        int col = w * 192 + cf * 16 + lr;
        float bias = bd[col];
        #pragma unroll
        for (int j = 0; j < 4; j++) {
            float v = acc[cf][j] + bias;
            acc[cf][j] = v;
            sum[j] += v;
            sq[j] += v * v;
        }
    }
    #pragma unroll
    for (int j = 0; j < 4; j++) {
        float s = sum[j], q = sq[j];
        s += __shfl_xor(s, 1); q += __shfl_xor(q, 1);
        s += __shfl_xor(s, 2); q += __shfl_xor(q, 2);
        s += __shfl_xor(s, 4); q += __shfl_xor(q, 4);
        s += __shfl_xor(s, 8); q += __shfl_xor(q, 8);
        sum[j] = s; sq[j] = q;
    }
    if (lr == 0) {
        #pragma unroll
        for (int j = 0; j < 4; j++) {
            part[0][w][lg * 4 + j] = sum[j];
            part[1][w][lg * 4 + j] = sq[j];
        }
    }
    __syncthreads();
    float mu[4], rstd[4];
    #pragma unroll
    for (int j = 0; j < 4; j++) {
        int row = lg * 4 + j;
        float S = part[0][0][row] + part[0][1][row] + part[0][2][row] + part[0][3][row];
        float Q = part[1][0][row] + part[1][1][row] + part[1][2][row] + part[1][3][row];
        mu[j] = S * (1.0f / 768.0f);
        float var = Q * (1.0f / 768.0f) - mu[j] * mu[j];
        rstd[j] = rsqrtf(var + 1e-12f);
    }
    // normalize + affine -> hsn bf16 -> buf (safe: pass-2 reads done pre-barrier)
    #pragma unroll
    for (int cf = 0; cf < 12; cf++) {
        int col = w * 192 + cf * 16 + lr;
        float g = lng[col], bb = lnb[col];
        #pragma unroll
        for (int j = 0; j < 4; j++) {
            int row = lg * 4 + j;
            float hn = (acc[cf][j] - mu[j]) * rstd[j] * g + bb;
            buf[SWZ(row, col)] = f2bf(hn);
        }
    }
    __syncthreads();

    // ---- out projection (wave 0): out = hsn @ WcT + bc
    if (w == 0) {
        f32x4 oa = {0, 0, 0, 0};
        #pragma unroll 4
        for (int k0 = 0; k0 < DD; k0 += 32) {
            bfrag a = *(const bfrag*)&buf[SWZ(lr, k0 + lg * 8)];
            bfrag b = ldg8(wcT + (size_t)lr * DD + k0 + lg * 8);
            oa = MFMA(a, b, oa);
        }
        #pragma unroll
        for (int j = 0; j < 4; j++)
            out[(size_t)(row0 + lg * 4 + j) * NCOUT + lr] = oa[j] + bc[lr];
    }
}

// ---------------------------------------------------------------------------
extern "C" void kernel_launch(void* const* d_in, const int* in_sizes, int n_in,
                              void* d_out, int out_size, void* d_ws, size_t ws_size,
                              hipStream_t stream)
{
    const float* hidden = (const float*)d_in[0];
    const int*   mask   = (const int*)d_in[1];
    const int*   rnd    = (const int*)d_in[2];
    const float* Wq = (const float*)d_in[3];
    const float* bq = (const float*)d_in[4];
    const float* Wk = (const float*)d_in[5];
    const float* bk = (const float*)d_in[6];
    const float* Wv = (const float*)d_in[7];
    const float* bv = (const float*)d_in[8];
    const float* Wo = (const float*)d_in[9];
    const float* bo = (const float*)d_in[10];
    const float* Wd = (const float*)d_in[11];
    const float* bd = (const float*)d_in[12];
    const float* lng = (const float*)d_in[13];
    const float* lnb = (const float*)d_in[14];
    const float* Wc = (const float*)d_in[15];
    const float* bc = (const float*)d_in[16];
    float* out = (float*)d_out;

    // Only the LAST layer's hidden state reaches the output (out = hs[-1]).
    int L = in_sizes[0] / (TT * DD);
    const float* X = hidden + (size_t)(L - 1) * TT * DD;

    const size_t TD  = (size_t)TT * DD;     // 786432
    const size_t WSZ = (size_t)DD * DD;     // 589824

    ushort* xb   = (ushort*)d_ws;
    ushort* wqT  = xb   + TD;
    ushort* wkT  = wqT  + WSZ;
    ushort* wvT  = wkT  + WSZ;
    ushort* woT  = wvT  + WSZ;
    ushort* wdT  = woT  + WSZ;
    ushort* wcT  = wdT  + WSZ;              // 16*768
    ushort* qbf  = wcT  + (size_t)NCOUT * DD;
    ushort* kbf  = qbf  + TD;
    ushort* vTb  = kbf  + TD;
    ushort* ctxb = vTb  + TD;

    prep_k<<<3660, 256, 0, stream>>>(X, Wq, Wk, Wv, Wo, Wd, Wc,
                                     xb, wqT, wkT, wvT, woT, wdT, wcT);
    qkv_mfma_k<<<dim3(16, NHEAD, 3), 256, 0, stream>>>(xb, wqT, wkT, wvT,
                                                       bq, bk, bv, qbf, kbf, vTb);
    attn_k<<<dim3(64, NHEAD), 256, 0, stream>>>(qbf, kbf, vTb, mask, rnd, ctxb);
    tail_k<<<64, 256, 0, stream>>>(ctxb, woT, bo, wdT, bd, lng, lnb, wcT, bc, out);
}

// Round 7
// 120.090 us; speedup vs baseline: 1.2208x; 1.2208x over previous
//
#include <hip/hip_runtime.h>
#include <hip/hip_bf16.h>
#include <math.h>

#define TT    1024   // B*S tokens
#define DD    768    // hidden dim
#define NHEAD 12
#define HDIM  64
#define NBLK  16
#define NMID  14
#define NCOUT 16

typedef __attribute__((ext_vector_type(4))) float f32x4;
typedef __attribute__((ext_vector_type(8))) short bfrag;   // 8 bf16 = 4 VGPRs

#define MFMA(a, b, c) __builtin_amdgcn_mfma_f32_16x16x32_bf16(a, b, c, 0, 0, 0)

__device__ __forceinline__ bfrag ldg8(const ushort* p) { return *(const bfrag*)p; }
__device__ __forceinline__ ushort f2bf(float f) {
    __hip_bfloat16 h = __float2bfloat16(f);
    return *(ushort*)&h;
}

// ---------------------------------------------------------------------------
// Fused prep: blocks [0,768) convert X fp32->bf16; blocks [768, 768+2880)
// transpose+convert the 5 weight matrices W[k][n] -> WT[n][k] bf16.
// ---------------------------------------------------------------------------
__global__ __launch_bounds__(256) void prep_k(
    const float* __restrict__ X,
    const float* __restrict__ Wq, const float* __restrict__ Wk,
    const float* __restrict__ Wv, const float* __restrict__ Wo,
    const float* __restrict__ Wd,
    ushort* __restrict__ xb,
    ushort* __restrict__ qT, ushort* __restrict__ kT, ushort* __restrict__ vT,
    ushort* __restrict__ oT, ushort* __restrict__ dT)
{
    __shared__ float t[32][33];
    int bx = blockIdx.x;
    if (bx < 768) {                                  // X conversion
        int i = bx * 256 + threadIdx.x;              // float4 index
        float4 f = ((const float4*)X)[i];
        ushort4 u;
        u.x = f2bf(f.x); u.y = f2bf(f.y); u.z = f2bf(f.z); u.w = f2bf(f.w);
        ((ushort4*)xb)[i] = u;
        return;
    }
    int bz = bx - 768;                               // 0..2879
    int z = bz / 576;
    int rem = bz % 576;
    int k0 = (rem / 24) * 32, n0 = (rem % 24) * 32;
    const float* W; ushort* O;
    if (z == 0)      { W = Wq; O = qT; }
    else if (z == 1) { W = Wk; O = kT; }
    else if (z == 2) { W = Wv; O = vT; }
    else if (z == 3) { W = Wo; O = oT; }
    else             { W = Wd; O = dT; }
    int tx = threadIdx.x & 31, ty = threadIdx.x >> 5;   // ty 0..7
    #pragma unroll
    for (int i = 0; i < 4; i++)
        t[ty + i * 8][tx] = W[(k0 + ty + i * 8) * DD + n0 + tx];
    __syncthreads();
    #pragma unroll
    for (int i = 0; i < 4; i++)
        O[(n0 + ty + i * 8) * DD + k0 + tx] = f2bf(t[tx][ty + i * 8]);
}

// ---------------------------------------------------------------------------
// QKV MFMA GEMM, K-split: grid (64, 12, 3). Block = 16 rows x 64 cols (one
// head). Wave w covers K range [w*192,(w+1)*192) over all 4 col-frags;
// partials merged via LDS (fp32 add), bias added after merge.
// ---------------------------------------------------------------------------
__global__ __launch_bounds__(256) void qkv_mfma_k(
    const ushort* __restrict__ xb,
    const ushort* __restrict__ wqT, const ushort* __restrict__ wkT,
    const ushort* __restrict__ wvT,
    const float* __restrict__ bq, const float* __restrict__ bk,
    const float* __restrict__ bv,
    ushort* __restrict__ qo, ushort* __restrict__ ko, ushort* __restrict__ vTo)
{
    int z = blockIdx.z;
    const ushort* BT = (z == 0) ? wqT : (z == 1) ? wkT : wvT;
    const float* bias = (z == 0) ? bq : (z == 1) ? bk : bv;

    __shared__ float mo[4][4][4][64];   // [wave][nt][j][lane] = 16KB
    int lane = threadIdx.x & 63, w = threadIdx.x >> 6;
    int lr = lane & 15, lg = lane >> 4;
    int row0 = blockIdx.x * 16;
    int h = blockIdx.y;
    int col0 = h * 64;

    f32x4 acc[4];
    #pragma unroll
    for (int nt = 0; nt < 4; nt++) acc[nt] = (f32x4){0, 0, 0, 0};
    const ushort* ap = xb + (size_t)(row0 + lr) * DD + w * 192 + lg * 8;
    const ushort* bp = BT + (size_t)(col0 + lr) * DD + w * 192 + lg * 8;
    #pragma unroll
    for (int ks = 0; ks < 6; ks++) {
        bfrag a = ldg8(ap + ks * 32);
        #pragma unroll
        for (int nt = 0; nt < 4; nt++) {
            bfrag b = ldg8(bp + (size_t)nt * 16 * DD + ks * 32);
            acc[nt] = MFMA(a, b, acc[nt]);
        }
    }
    #pragma unroll
    for (int nt = 0; nt < 4; nt++)
        #pragma unroll
        for (int j = 0; j < 4; j++)
            mo[w][nt][j][lane] = acc[nt][j];
    __syncthreads();

    // wave w merges col-frag nt=w and stores
    #pragma unroll
    for (int j = 0; j < 4; j++) {
        float of = mo[0][w][j][lane] + mo[1][w][j][lane] +
                   mo[2][w][j][lane] + mo[3][w][j][lane];
        int r = row0 + lg * 4 + j;
        int cc = w * 16 + lr;                      // col within head
        ushort u = f2bf(of + bias[col0 + cc]);
        if (z == 2)      vTo[(size_t)(h * 64 + cc) * TT + r] = u;
        else if (z == 0) qo[(size_t)(h * TT + r) * 64 + cc] = u;
        else             ko[(size_t)(h * TT + r) * 64 + cc] = u;
    }
}

// ---------------------------------------------------------------------------
// Generic MFMA GEMM, K-split: A[1024][768] bf16 @ BT + bias. Grid (64,12);
// block = 16 rows x 64 cols; wave w = K-quarter; LDS merge.
// OUTF32=0 -> bf16 out, OUTF32=1 -> f32 out.
// ---------------------------------------------------------------------------
template <int OUTF32>
__global__ __launch_bounds__(256) void mm_mfma_k(
    const ushort* __restrict__ A, const ushort* __restrict__ BT,
    const float* __restrict__ bias, void* __restrict__ out)
{
    __shared__ float mo[4][4][4][64];   // [wave][nt][j][lane] = 16KB
    int lane = threadIdx.x & 63, w = threadIdx.x >> 6;
    int lr = lane & 15, lg = lane >> 4;
    int row0 = blockIdx.x * 16;
    int col0 = blockIdx.y * 64;

    f32x4 acc[4];
    #pragma unroll
    for (int nt = 0; nt < 4; nt++) acc[nt] = (f32x4){0, 0, 0, 0};
    const ushort* ap = A + (size_t)(row0 + lr) * DD + w * 192 + lg * 8;
    const ushort* bp = BT + (size_t)(col0 + lr) * DD + w * 192 + lg * 8;
    #pragma unroll
    for (int ks = 0; ks < 6; ks++) {
        bfrag a = ldg8(ap + ks * 32);
        #pragma unroll
        for (int nt = 0; nt < 4; nt++) {
            bfrag b = ldg8(bp + (size_t)nt * 16 * DD + ks * 32);
            acc[nt] = MFMA(a, b, acc[nt]);
        }
    }
    #pragma unroll
    for (int nt = 0; nt < 4; nt++)
        #pragma unroll
        for (int j = 0; j < 4; j++)
            mo[w][nt][j][lane] = acc[nt][j];
    __syncthreads();

    #pragma unroll
    for (int j = 0; j < 4; j++) {
        float of = mo[0][w][j][lane] + mo[1][w][j][lane] +
                   mo[2][w][j][lane] + mo[3][w][j][lane];
        int r = row0 + lg * 4 + j;
        int c = col0 + w * 16 + lr;
        float v = of + bias[c];
        if (OUTF32) ((float*)out)[(size_t)r * DD + c] = v;
        else        ((ushort*)out)[(size_t)r * DD + c] = f2bf(v);
    }
}

// ---------------------------------------------------------------------------
// Attention wave core (k-split): 16 q-rows vs NKB key blocks.
// S = Q K^T via MFMA -> scale/mask/exp -> P (bf16, swizzled per-wave LDS)
// -> O += P V via MFMA. Partial o/lsum merge by plain add (no-max softmax).
// ---------------------------------------------------------------------------
template <int NKB>
__device__ __forceinline__ void attn_core(
    const ushort* __restrict__ kbf, const ushort* __restrict__ vT,
    const int* __restrict__ mask, const int kblk[NKB], int h,
    bfrag aq0, bfrag aq1, ushort* __restrict__ Pw,
    f32x4 (&o)[4], float (&lsum)[4])
{
    int lane = threadIdx.x & 63, lr = lane & 15, lg = lane >> 4;
    #pragma unroll
    for (int kb = 0; kb < NKB; kb++) {
        int bi = kblk[kb];
        #pragma unroll
        for (int kt = 0; kt < 4; kt++) {
            int key = bi * 64 + kt * 16 + lr;
            const ushort* krow = kbf + (size_t)(h * TT + key) * 64 + lg * 8;
            bfrag b0 = ldg8(krow);
            bfrag b1 = ldg8(krow + 32);
            f32x4 s = {0, 0, 0, 0};
            s = MFMA(aq0, b0, s);
            s = MFMA(aq1, b1, s);
            int mk = mask[key];
            #pragma unroll
            for (int j = 0; j < 4; j++) {
                float pv = (mk > 0) ? __expf(s[j] * 0.125f) : 0.0f;
                lsum[j] += pv;
                int row = lg * 4 + j;
                int idx = (row * (NKB * 64) + (kb * 4 + kt) * 16 + lr)
                          ^ ((row & 7) << 3);
                Pw[idx] = f2bf(pv);
            }
        }
    }
    #pragma unroll
    for (int ks = 0; ks < NKB * 2; ks++) {     // 32-key chunks
        int bi = kblk[ks >> 1];
        int pidx = (lr * (NKB * 64) + ks * 32 + lg * 8) ^ ((lr & 7) << 3);
        bfrag pa = *(const bfrag*)(Pw + pidx);
        #pragma unroll
        for (int dt = 0; dt < 4; dt++) {
            const ushort* vrow = vT + (size_t)(h * 64 + dt * 16 + lr) * TT
                               + bi * 64 + (ks & 1) * 32 + lg * 8;
            o[dt] = MFMA(pa, ldg8(vrow), o[dt]);
        }
    }
}

// ---------------------------------------------------------------------------
// Attention, k-split across waves. Grid (64, 12): x = 16-row q-tile, y = head.
// qb = x>>2. Mid (qb 1..14): wave w covers 2 of the 8 gathered key blocks.
// Glob (qb 0,15): wave w covers key blocks 4w..4w+3. Cross-wave merge via
// LDS add (valid because no-max softmax partials are plain sums), then wave w
// normalizes and writes output columns w*16..w*16+15.
// ---------------------------------------------------------------------------
__global__ __launch_bounds__(256) void attn_k(
    const ushort* __restrict__ qbf, const ushort* __restrict__ kbf,
    const ushort* __restrict__ vT, const int* __restrict__ mask,
    const int* __restrict__ rnd, ushort* __restrict__ ctx)
{
    __shared__ ushort P[4][16 * 256];
    __shared__ float mo[4][4][4][64];   // [wave][dt][j][lane], conflict-free
    __shared__ float ml[4][16];
    int x = blockIdx.x, h = blockIdx.y;
    int w = threadIdx.x >> 6, lane = threadIdx.x & 63;
    int lr = lane & 15, lg = lane >> 4;

    int qtok0 = x * 16;
    int qb = x >> 2;
    const ushort* qrow = qbf + (size_t)(h * TT + qtok0 + lr) * 64 + lg * 8;
    bfrag aq0 = ldg8(qrow);
    bfrag aq1 = ldg8(qrow + 32);

    f32x4 zero = {0, 0, 0, 0};
    f32x4 o[4] = {zero, zero, zero, zero};
    float l[4] = {0.f, 0.f, 0.f, 0.f};

    if (qb >= 1 && qb <= NMID) {
        int n = qb - 1;
        int b0, b1;
        if (w == 0)      { b0 = 0;              b1 = NBLK - 1;       }
        else if (w == 1) { b0 = n;              b1 = n + 1;          }
        else if (w == 2) { b0 = n + 2;          b1 = rnd[n * 3 + 0]; }
        else             { b0 = rnd[n * 3 + 1]; b1 = rnd[n * 3 + 2]; }
        int kblk[2] = { b0, b1 };
        attn_core<2>(kbf, vT, mask, kblk, h, aq0, aq1, &P[w][0], o, l);
    } else {
        int kblk[4] = { w * 4, w * 4 + 1, w * 4 + 2, w * 4 + 3 };
        attn_core<4>(kbf, vT, mask, kblk, h, aq0, aq1, &P[w][0], o, l);
    }

    // wave-local row-sum reduce (over lr bits), then stage partials in LDS
    #pragma unroll
    for (int j = 0; j < 4; j++) {
        float s = l[j];
        s += __shfl_xor(s, 1); s += __shfl_xor(s, 2);
        s += __shfl_xor(s, 4); s += __shfl_xor(s, 8);
        l[j] = s;
    }
    #pragma unroll
    for (int dt = 0; dt < 4; dt++)
        #pragma unroll
        for (int j = 0; j < 4; j++)
            mo[w][dt][j][lane] = o[dt][j];
    if (lr == 0) {
        #pragma unroll
        for (int j = 0; j < 4; j++) ml[w][lg * 4 + j] = l[j];
    }
    __syncthreads();

    // wave w merges + writes output columns w*16 .. w*16+15
    float lt[4];
    #pragma unroll
    for (int j = 0; j < 4; j++)
        lt[j] = 1.0f / (ml[0][lg * 4 + j] + ml[1][lg * 4 + j] +
                        ml[2][lg * 4 + j] + ml[3][lg * 4 + j]);
    #pragma unroll
    for (int j = 0; j < 4; j++) {
        float of = mo[0][w][j][lane] + mo[1][w][j][lane] +
                   mo[2][w][j][lane] + mo[3][w][j][lane];
        ctx[(size_t)(qtok0 + lg * 4 + j) * DD + h * 64 + w * 16 + lr] =
            f2bf(of * lt[j]);
    }
}

// ---------------------------------------------------------------------------
// Fused LayerNorm + final projection. One block per token:
// LN(hs row) -> LDS -> out[t,0:16] = hsn @ Wc + bc.
// ---------------------------------------------------------------------------
__global__ __launch_bounds__(256) void ln_out_k(
    const float* __restrict__ hs, const float* __restrict__ g,
    const float* __restrict__ b, const float* __restrict__ Wc,
    const float* __restrict__ bc, float* __restrict__ out)
{
    int t = blockIdx.x;
    int tid = threadIdx.x;
    __shared__ float red[256];
    __shared__ float hsn[768];

    float x0 = hs[t * DD + tid];
    float x1 = hs[t * DD + tid + 256];
    float x2 = hs[t * DD + tid + 512];

    red[tid] = x0 + x1 + x2;
    __syncthreads();
    for (int off = 128; off > 0; off >>= 1) {
        if (tid < off) red[tid] += red[tid + off];
        __syncthreads();
    }
    float mean = red[0] * (1.0f / 768.0f);
    __syncthreads();

    float d0 = x0 - mean, d1 = x1 - mean, d2 = x2 - mean;
    red[tid] = d0 * d0 + d1 * d1 + d2 * d2;
    __syncthreads();
    for (int off = 128; off > 0; off >>= 1) {
        if (tid < off) red[tid] += red[tid + off];
        __syncthreads();
    }
    float var = red[0] * (1.0f / 768.0f);
    float rstd = rsqrtf(var + 1e-12f);

    hsn[tid]       = d0 * rstd * g[tid]       + b[tid];
    hsn[tid + 256] = d1 * rstd * g[tid + 256] + b[tid + 256];
    hsn[tid + 512] = d2 * rstd * g[tid + 512] + b[tid + 512];
    __syncthreads();

    // out projection: 16 cols x 16 threads/col
    int c = tid >> 4, i = tid & 15;
    float s = 0.0f;
    #pragma unroll 8
    for (int j = 0; j < 48; j++) {
        int kk = i * 48 + j;
        s += hsn[kk] * Wc[kk * NCOUT + c];
    }
    s += __shfl_xor(s, 1); s += __shfl_xor(s, 2);
    s += __shfl_xor(s, 4); s += __shfl_xor(s, 8);
    if (i == 0) out[t * NCOUT + c] = s + bc[c];
}

// ---------------------------------------------------------------------------
extern "C" void kernel_launch(void* const* d_in, const int* in_sizes, int n_in,
                              void* d_out, int out_size, void* d_ws, size_t ws_size,
                              hipStream_t stream)
{
    const float* hidden = (const float*)d_in[0];
    const int*   mask   = (const int*)d_in[1];
    const int*   rnd    = (const int*)d_in[2];
    const float* Wq = (const float*)d_in[3];
    const float* bq = (const float*)d_in[4];
    const float* Wk = (const float*)d_in[5];
    const float* bk = (const float*)d_in[6];
    const float* Wv = (const float*)d_in[7];
    const float* bv = (const float*)d_in[8];
    const float* Wo = (const float*)d_in[9];
    const float* bo = (const float*)d_in[10];
    const float* Wd = (const float*)d_in[11];
    const float* bd = (const float*)d_in[12];
    const float* lng = (const float*)d_in[13];
    const float* lnb = (const float*)d_in[14];
    const float* Wc = (const float*)d_in[15];
    const float* bc = (const float*)d_in[16];
    float* out = (float*)d_out;

    // Only the LAST layer's hidden state reaches the output (out = hs[-1]).
    int L = in_sizes[0] / (TT * DD);
    const float* X = hidden + (size_t)(L - 1) * TT * DD;

    const size_t TD  = (size_t)TT * DD;     // 786432
    const size_t WSZ = (size_t)DD * DD;     // 589824

    ushort* xb   = (ushort*)d_ws;
    ushort* wqT  = xb   + TD;
    ushort* wkT  = wqT  + WSZ;
    ushort* wvT  = wkT  + WSZ;
    ushort* woT  = wvT  + WSZ;
    ushort* wdT  = woT  + WSZ;
    ushort* qbf  = wdT  + WSZ;
    ushort* kbf  = qbf  + TD;
    ushort* vTb  = kbf  + TD;
    ushort* ctxb = vTb  + TD;
    ushort* attb = ctxb + TD;
    float*  hs   = (float*)(attb + TD);

    prep_k<<<768 + 2880, 256, 0, stream>>>(X, Wq, Wk, Wv, Wo, Wd,
                                           xb, wqT, wkT, wvT, woT, wdT);
    qkv_mfma_k<<<dim3(64, NHEAD, 3), 256, 0, stream>>>(xb, wqT, wkT, wvT,
                                                       bq, bk, bv, qbf, kbf, vTb);
    attn_k<<<dim3(64, NHEAD), 256, 0, stream>>>(qbf, kbf, vTb, mask, rnd, ctxb);
    mm_mfma_k<0><<<dim3(64, NHEAD), 256, 0, stream>>>(ctxb, woT, bo, attb);
    mm_mfma_k<1><<<dim3(64, NHEAD), 256, 0, stream>>>(attb, wdT, bd, hs);
    ln_out_k<<<TT, 256, 0, stream>>>(hs, lng, lnb, Wc, bc, out);
}